// Round 15
// baseline (23.639 us; speedup 1.0000x reference)
//
#include <hip/hip_runtime.h>
#include <math.h>

#define EPSF 1e-8f

constexpr int B = 512;
constexpr int F = 256;

using frag_ab = __attribute__((ext_vector_type(8))) short;   // 8 bf16
using f32x4   = __attribute__((ext_vector_type(4))) float;

__device__ __forceinline__ unsigned short f2bf(float f) {
    unsigned int u = __float_as_uint(f);
    unsigned int r = (u + 0x7fffu + ((u >> 16) & 1u)) >> 16;   // RNE
    return (unsigned short)r;
}

// ---- K1: bf16 Gram tile GEMM (R10 verbatim) + block-0 side job (R13) ------
// Diagonal tiles emit invs[row]; block 0 zeroes out[0] and computes the
// global valid-row count V from the 16-pattern ballot histogram.
__global__ __launch_bounds__(64) void gram_mfma(
    const float* __restrict__ feats, const int* __restrict__ ids,
    float* __restrict__ gram, float* __restrict__ invs,
    float* __restrict__ Vout, float* __restrict__ out)
{
    const int bid = blockIdx.x;
    const int it = bid >> 5, jt = bid & 31;      // 32x32 grid of 16x16 tiles
    const int l = threadIdx.x;

    __shared__ __align__(16) unsigned char Abf[16 * 512];   // 16 rows x 512 B
    __shared__ __align__(16) unsigned char Bbf[16 * 512];

    if (bid == 0) {                              // side job (proven R13)
        if (l == 0) out[0] = 0.f;
        int pj[8];
        #pragma unroll
        for (int q = 0; q < 8; ++q) {
            int4 v = ((const int4*)ids)[q * 64 + l];
            pj[q] = (v.x & 1) | ((v.y & 1) << 1) | ((v.z & 1) << 2) | ((v.w & 1) << 3);
        }
        int V = 0;
        #pragma unroll
        for (int p = 0; p < 16; ++p) {
            int c = 0;
            #pragma unroll
            for (int q = 0; q < 8; ++q)
                c += (int)__popcll(__ballot(pj[q] == p));
            V += (c >= 2 && c <= B - 1) ? c : 0;  // rows with ns>0 && nd>0
        }
        if (l == 0) Vout[0] = (float)V;
    }

    const float4* Ag = (const float4*)(feats + (size_t)(it * 16) * F);
    const float4* Bg = (const float4*)(feats + (size_t)(jt * 16) * F);

    #pragma unroll
    for (int m = 0; m < 16; ++m) {               // row m, lane l = float4 #l
        const int swz = ((l >> 1) ^ (m & 7)) * 16 + (l & 1) * 8;
        float4 a = Ag[m * 64 + l];
        ushort4 ha = { f2bf(a.x), f2bf(a.y), f2bf(a.z), f2bf(a.w) };
        *(ushort4*)(Abf + m * 512 + swz) = ha;
        float4 b = Bg[m * 64 + l];
        ushort4 hb = { f2bf(b.x), f2bf(b.y), f2bf(b.z), f2bf(b.w) };
        *(ushort4*)(Bbf + m * 512 + swz) = hb;
    }
    // single wave: compiler orders ds_write -> ds_read via lgkmcnt

    const int row_f = l & 15;
    const int kg    = l >> 4;
    f32x4 acc = {0.f, 0.f, 0.f, 0.f};
    #pragma unroll
    for (int kc = 0; kc < 8; ++kc) {
        int cc = (kc * 4 + kg) ^ (row_f & 7);
        frag_ab a = *(const frag_ab*)(Abf + row_f * 512 + cc * 16);
        frag_ab b = *(const frag_ab*)(Bbf + row_f * 512 + cc * 16);
        acc = __builtin_amdgcn_mfma_f32_16x16x32_bf16(a, b, acc, 0, 0, 0);
    }
    // C layout (verified): col = lane&15, row = (lane>>4)*4 + j
    const int col = l & 15;
    #pragma unroll
    for (int j = 0; j < 4; ++j) {
        int row = kg * 4 + j;
        float v = acc[j];
        gram[(size_t)(it * 16 + row) * B + jt * 16 + col] = v;
        if (it == jt && col == row)              // gram[r][r] -> inverse norm
            invs[it * 16 + row] = 1.f / fmaxf(sqrtf(v + EPSF), EPSF);
    }
}

// ---- K2: 32 blocks x 256 thr; wave w does 4 rows; 1 atomicAdd per block ---
__global__ __launch_bounds__(256) void rows_fused(
    const int* __restrict__ ids, const float* __restrict__ gram,
    const float* __restrict__ invs, const float* __restrict__ Vin,
    float* __restrict__ out)
{
    const int w = threadIdx.x >> 6, l = threadIdx.x & 63;

    __shared__ float vals[4][B];                 // 8 KB, one row-buffer per wave
    __shared__ float wacc[4];

    // hoisted per-wave: lane l's 8 j-slots (patterns + inverse norms)
    int   pj[8];
    float invj[8];
    #pragma unroll
    for (int q = 0; q < 8; ++q) {
        const int j = q * 64 + l;
        int4 v = ((const int4*)ids)[j];          // coalesced
        pj[q] = (v.x & 1) | ((v.y & 1) << 1) | ((v.z & 1) << 2) | ((v.w & 1) << 3);
        invj[q] = invs[j];                       // coalesced
    }
    const float V = Vin[0];
    const unsigned long long lmask = (1ull << l) - 1ull;

    float acc = 0.f;                             // lane0-only accumulator
    #pragma unroll
    for (int r = 0; r < 4; ++r) {
        const int i = blockIdx.x * 16 + w * 4 + r;
        const int4 idi = ((const int4*)ids)[i];  // wave-uniform
        const int pi = (idi.x & 1) | ((idi.y & 1) << 1)
                     | ((idi.z & 1) << 2) | ((idi.w & 1) << 3);
        const float invi = invs[i];

        float cosv[8];
        #pragma unroll
        for (int q = 0; q < 8; ++q)
            cosv[q] = gram[(size_t)i * B + q * 64 + l] * invi * invj[q];

        // running-ballot compaction of the sim set (deterministic order)
        int off = 0;
        #pragma unroll
        for (int q = 0; q < 8; ++q) {
            const int j = q * 64 + l;
            const bool sim = (pj[q] == pi) && (j != i);
            const unsigned long long m = __ballot(sim);
            if (sim) vals[w][off + (int)__popcll(m & lmask)] = cosv[q];
            off += (int)__popcll(m);
        }
        const int ns = off;

        float b[8];                              // sentinel for sim slots
        #pragma unroll
        for (int q = 0; q < 8; ++q)
            b[q] = (pj[q] != pi) ? 0.15f * (float)__popc(pj[q] ^ pi) + cosv[q]
                                 : -1e30f;

        float sa[8] = {0.f, 0.f, 0.f, 0.f, 0.f, 0.f, 0.f, 0.f};
        for (int t = 0; t < ns; ++t) {
            const float a = vals[w][t];          // broadcast LDS read
            #pragma unroll
            for (int q = 0; q < 8; ++q) sa[q] += fmaxf(0.f, b[q] - a);
        }
        float s = ((sa[0] + sa[1]) + (sa[2] + sa[3]))
                + ((sa[4] + sa[5]) + (sa[6] + sa[7]));
        #pragma unroll
        for (int o = 32; o > 0; o >>= 1) s += __shfl_down(s, o);

        if (l == 0) {
            const int nd = (B - 1) - ns;         // j != i is sim xor dif
            const long cnt = (long)ns * (long)nd;
            if (cnt > 0) acc += (s / (float)cnt) / V;
        }
    }

    if (l == 0) wacc[w] = acc;
    __syncthreads();
    if (threadIdx.x == 0) {
        float t = (wacc[0] + wacc[1]) + (wacc[2] + wacc[3]);
        atomicAdd(out, t);                       // 32 atomics total
    }
}

extern "C" void kernel_launch(void* const* d_in, const int* in_sizes, int n_in,
                              void* d_out, int out_size, void* d_ws, size_t ws_size,
                              hipStream_t stream) {
    const int*   ids   = (const int*)d_in[0];
    const float* feats = (const float*)d_in[1];
    float* out = (float*)d_out;

    char* ws = (char*)d_ws;
    float* gram = (float*)ws;                    // 1 MB
    float* invs = (float*)(ws + (1u << 20));     // 2 KB
    float* Vws  = (float*)(ws + (1u << 20) + 2048);

    hipLaunchKernelGGL(gram_mfma, dim3(32 * 32), dim3(64), 0, stream,
                       feats, ids, gram, invs, Vws, out);
    hipLaunchKernelGGL(rows_fused, dim3(32), dim3(256), 0, stream,
                       ids, gram, invs, Vws, out);
}

// Round 16
// 15.954 us; speedup vs baseline: 1.4817x; 1.4817x over previous
//
#include <hip/hip_runtime.h>
#include <math.h>

#define EPSF 1e-8f

constexpr int B = 512;
constexpr int F = 256;

using frag_ab = __attribute__((ext_vector_type(8))) short;   // 8 bf16
using f32x4   = __attribute__((ext_vector_type(4))) float;

__device__ __forceinline__ unsigned short f2bf(float f) {
    unsigned int u = __float_as_uint(f);
    unsigned int r = (u + 0x7fffu + ((u >> 16) & 1u)) >> 16;   // RNE
    return (unsigned short)r;
}

// ---- K1: bf16 Gram tile GEMM, 1 wave per 16x16 tile, 1024 blocks ----------
// fp32->bf16 convert fused in staging; diagonal tiles emit invs[row] from
// the Gram diagonal. (R10 verbatim — measured best.)
__global__ __launch_bounds__(64) void gram_mfma(
    const float* __restrict__ feats, float* __restrict__ gram,
    float* __restrict__ invs)
{
    const int bid = blockIdx.x;
    const int it = bid >> 5, jt = bid & 31;      // 32x32 grid of 16x16 tiles
    const int l = threadIdx.x;

    __shared__ __align__(16) unsigned char Abf[16 * 512];   // 16 rows x 512 B
    __shared__ __align__(16) unsigned char Bbf[16 * 512];

    const float4* Ag = (const float4*)(feats + (size_t)(it * 16) * F);
    const float4* Bg = (const float4*)(feats + (size_t)(jt * 16) * F);

    #pragma unroll
    for (int m = 0; m < 16; ++m) {               // row m, lane l = float4 #l
        const int swz = ((l >> 1) ^ (m & 7)) * 16 + (l & 1) * 8;
        float4 a = Ag[m * 64 + l];
        ushort4 ha = { f2bf(a.x), f2bf(a.y), f2bf(a.z), f2bf(a.w) };
        *(ushort4*)(Abf + m * 512 + swz) = ha;
        float4 b = Bg[m * 64 + l];
        ushort4 hb = { f2bf(b.x), f2bf(b.y), f2bf(b.z), f2bf(b.w) };
        *(ushort4*)(Bbf + m * 512 + swz) = hb;
    }
    // single wave: compiler orders ds_write -> ds_read via lgkmcnt

    const int row_f = l & 15;
    const int kg    = l >> 4;
    f32x4 acc = {0.f, 0.f, 0.f, 0.f};
    #pragma unroll
    for (int kc = 0; kc < 8; ++kc) {
        int cc = (kc * 4 + kg) ^ (row_f & 7);
        frag_ab a = *(const frag_ab*)(Abf + row_f * 512 + cc * 16);
        frag_ab b = *(const frag_ab*)(Bbf + row_f * 512 + cc * 16);
        acc = __builtin_amdgcn_mfma_f32_16x16x32_bf16(a, b, acc, 0, 0, 0);
    }
    // C layout (verified): col = lane&15, row = (lane>>4)*4 + j
    const int col = l & 15;
    #pragma unroll
    for (int j = 0; j < 4; ++j) {
        int row = kg * 4 + j;
        float v = acc[j];
        gram[(size_t)(it * 16 + row) * B + jt * 16 + col] = v;
        if (it == jt && col == row)              // gram[r][r] -> inverse norm
            invs[it * 16 + row] = 1.f / fmaxf(sqrtf(v + EPSF), EPSF);
    }
}

// ---- K2: per-row hinge sums (R10 verbatim) --------------------------------
__global__ __launch_bounds__(256) void rows_kernel(
    const int* __restrict__ ids, const float* __restrict__ gram,
    const float* __restrict__ invs,
    float* __restrict__ rowloss, int* __restrict__ rowvalid)
{
    const int i    = blockIdx.x;
    const int tid  = threadIdx.x;
    const int lane = tid & 63;
    const int wid  = tid >> 6;

    __shared__ unsigned char pat[B];
    __shared__ float sinv[B];
    __shared__ float vals[B];
    __shared__ unsigned long long cmask[8];
    __shared__ int   coff[9];
    __shared__ float part_s[4];

    #pragma unroll
    for (int q = 0; q < 2; ++q) {
        int j = tid + q * 256;
        int4 v = ((const int4*)ids)[j];
        pat[j] = (unsigned char)((v.x & 1) | ((v.y & 1) << 1)
                               | ((v.z & 1) << 2) | ((v.w & 1) << 3));
        sinv[j] = invs[j];                        // coalesced
    }
    __syncthreads();

    const int   pi   = pat[i];
    const float invi = sinv[i];

    // ballot-compact sim cos values (proven pattern)
    #pragma unroll
    for (int cc = 0; cc < 2; ++cc) {
        int chunk = wid * 2 + cc;
        int j = chunk * 64 + lane;
        unsigned long long m = __ballot(pat[j] == pi && j != i);
        if (lane == 0) cmask[chunk] = m;
    }
    __syncthreads();
    if (tid == 0) {
        int a = 0;
        #pragma unroll
        for (int c = 0; c < 8; ++c) { coff[c] = a; a += (int)__popcll(cmask[c]); }
        coff[8] = a;
    }
    __syncthreads();
    #pragma unroll
    for (int cc = 0; cc < 2; ++cc) {
        int chunk = wid * 2 + cc;
        int j = chunk * 64 + lane;
        unsigned long long m = cmask[chunk];
        if ((m >> lane) & 1ull) {
            int pos = coff[chunk] + (int)__popcll(m & ((1ull << lane) - 1ull));
            vals[pos] = gram[(size_t)i * B + j] * invi * sinv[j];
        }
    }
    __syncthreads();

    const int ns = coff[8];
    const int p0 = pat[tid], p1 = pat[tid + 256];
    const bool m0 = (p0 != pi), m1 = (p1 != pi);  // j==i auto-excluded (p==pi)
    const float c0 = gram[(size_t)i * B + tid]       * invi * sinv[tid];
    const float c1 = gram[(size_t)i * B + tid + 256] * invi * sinv[tid + 256];
    const float b0 = 0.15f * (float)__popc(p0 ^ pi) + c0;
    const float b1 = 0.15f * (float)__popc(p1 ^ pi) + c1;

    float s = 0.f;
    for (int t = 0; t < ns; ++t) {                // ~31 iters, broadcast LDS read
        float a = vals[t];
        if (m0) s += fmaxf(0.f, b0 - a);
        if (m1) s += fmaxf(0.f, b1 - a);
    }
    #pragma unroll
    for (int o = 32; o > 0; o >>= 1) s += __shfl_down(s, o);
    if (lane == 0) part_s[wid] = s;
    __syncthreads();
    if (tid == 0) {
        float tot = part_s[0] + part_s[1] + part_s[2] + part_s[3];
        const int nd = (B - 1) - ns;              // j != i is sim xor dif
        long cnt = (long)ns * (long)nd;
        rowloss[i]  = (cnt > 0) ? tot / (float)cnt : 0.f;
        rowvalid[i] = (cnt > 0) ? 1 : 0;
    }
}

// ---- K3: final mean over valid rows (R10 verbatim) ------------------------
__global__ __launch_bounds__(256) void finalize_kernel(
    const float* __restrict__ rowloss, const int* __restrict__ rowvalid,
    float* __restrict__ out)
{
    const int tid  = threadIdx.x;
    const int lane = tid & 63;
    const int wid  = tid >> 6;
    __shared__ float sb[4], vb[4];

    float s = rowloss[tid] + rowloss[tid + 256];
    float v = (float)(rowvalid[tid] + rowvalid[tid + 256]);
    #pragma unroll
    for (int o = 32; o > 0; o >>= 1) {
        s += __shfl_down(s, o);
        v += __shfl_down(v, o);
    }
    if (lane == 0) { sb[wid] = s; vb[wid] = v; }
    __syncthreads();
    if (tid == 0) {
        float ts = sb[0] + sb[1] + sb[2] + sb[3];
        float tv = vb[0] + vb[1] + vb[2] + vb[3];
        out[0] = ts / fmaxf(tv, 1.f);
    }
}

extern "C" void kernel_launch(void* const* d_in, const int* in_sizes, int n_in,
                              void* d_out, int out_size, void* d_ws, size_t ws_size,
                              hipStream_t stream) {
    const int*   ids   = (const int*)d_in[0];
    const float* feats = (const float*)d_in[1];
    float* out = (float*)d_out;

    char* ws = (char*)d_ws;
    float* gram     = (float*)ws;                           // 1 MB
    float* invs     = (float*)(ws + (1u << 20));            // 2 KB
    float* rowloss  = (float*)(ws + (1u << 20) + 2048);     // 2 KB
    int*   rowvalid = (int*)(ws + (1u << 20) + 4096);       // 2 KB

    hipLaunchKernelGGL(gram_mfma, dim3(32 * 32), dim3(64), 0, stream,
                       feats, gram, invs);
    hipLaunchKernelGGL(rows_kernel, dim3(B), dim3(256), 0, stream,
                       ids, gram, invs, rowloss, rowvalid);
    hipLaunchKernelGGL(finalize_kernel, dim3(1), dim3(256), 0, stream,
                       rowloss, rowvalid, out);
}

// Round 17
// 15.888 us; speedup vs baseline: 1.4878x; 1.0042x over previous
//
#include <hip/hip_runtime.h>
#include <math.h>

#define EPSF 1e-8f

constexpr int B = 512;
constexpr int F = 256;

using frag_ab = __attribute__((ext_vector_type(8))) short;   // 8 bf16
using f32x4   = __attribute__((ext_vector_type(4))) float;

__device__ __forceinline__ unsigned short f2bf(float f) {
    unsigned int u = __float_as_uint(f);
    unsigned int r = (u + 0x7fffu + ((u >> 16) & 1u)) >> 16;   // RNE
    return (unsigned short)r;
}

// ---- K1: bf16 Gram, 1 wave per 32x32 tile (2x2 of 16x16 MFMA), 256 blocks -
// Halves staging work vs the 16x16-tile version: each panel row staged once
// per 32-wide tile instead of once per 16-wide tile. Fragment path, swizzle
// ((16+row_f)&7 == row_f&7) and C layout identical to the proven kernel.
__global__ __launch_bounds__(64) void gram_mfma32(
    const float* __restrict__ feats, float* __restrict__ gram,
    float* __restrict__ invs)
{
    const int bid = blockIdx.x;
    const int it = bid >> 4, jt = bid & 15;      // 16x16 grid of 32x32 tiles
    const int l = threadIdx.x;

    __shared__ __align__(16) unsigned char Abf[32 * 512];   // 16 KB
    __shared__ __align__(16) unsigned char Bbf[32 * 512];   // 16 KB

    const float4* Ag = (const float4*)(feats + (size_t)(it * 32) * F);
    const float4* Bg = (const float4*)(feats + (size_t)(jt * 32) * F);

    #pragma unroll
    for (int m = 0; m < 32; ++m) {               // row m, lane l = float4 #l
        const int swz = ((l >> 1) ^ (m & 7)) * 16 + (l & 1) * 8;
        float4 a = Ag[m * 64 + l];
        ushort4 ha = { f2bf(a.x), f2bf(a.y), f2bf(a.z), f2bf(a.w) };
        *(ushort4*)(Abf + m * 512 + swz) = ha;
        float4 b = Bg[m * 64 + l];
        ushort4 hb = { f2bf(b.x), f2bf(b.y), f2bf(b.z), f2bf(b.w) };
        *(ushort4*)(Bbf + m * 512 + swz) = hb;
    }
    // single wave: compiler orders ds_write -> ds_read via lgkmcnt

    const int row_f = l & 15;
    const int kg    = l >> 4;
    f32x4 acc00 = {0,0,0,0}, acc01 = {0,0,0,0};
    f32x4 acc10 = {0,0,0,0}, acc11 = {0,0,0,0};
    #pragma unroll
    for (int kc = 0; kc < 8; ++kc) {
        int cc = (kc * 4 + kg) ^ (row_f & 7);
        frag_ab a0 = *(const frag_ab*)(Abf + (     row_f) * 512 + cc * 16);
        frag_ab a1 = *(const frag_ab*)(Abf + (16 + row_f) * 512 + cc * 16);
        frag_ab b0 = *(const frag_ab*)(Bbf + (     row_f) * 512 + cc * 16);
        frag_ab b1 = *(const frag_ab*)(Bbf + (16 + row_f) * 512 + cc * 16);
        acc00 = __builtin_amdgcn_mfma_f32_16x16x32_bf16(a0, b0, acc00, 0, 0, 0);
        acc01 = __builtin_amdgcn_mfma_f32_16x16x32_bf16(a0, b1, acc01, 0, 0, 0);
        acc10 = __builtin_amdgcn_mfma_f32_16x16x32_bf16(a1, b0, acc10, 0, 0, 0);
        acc11 = __builtin_amdgcn_mfma_f32_16x16x32_bf16(a1, b1, acc11, 0, 0, 0);
    }

    // C layout (verified): col = lane&15, row = kg*4 + j, per 16x16 sub-tile
    const int col = l & 15;
    #pragma unroll
    for (int j = 0; j < 4; ++j) {
        const int rl = kg * 4 + j;
        const size_t r0 = (size_t)(it * 32 + rl) * B;
        const size_t r1 = (size_t)(it * 32 + 16 + rl) * B;
        const int c0 = jt * 32 + col, c1 = jt * 32 + 16 + col;
        gram[r0 + c0] = acc00[j];
        gram[r0 + c1] = acc01[j];
        gram[r1 + c0] = acc10[j];
        gram[r1 + c1] = acc11[j];
        if (it == jt && col == rl) {             // diagonal -> inverse norms
            invs[it * 32 + rl]      = 1.f / fmaxf(sqrtf(acc00[j] + EPSF), EPSF);
            invs[it * 32 + 16 + rl] = 1.f / fmaxf(sqrtf(acc11[j] + EPSF), EPSF);
        }
    }
}

// ---- K2: per-row hinge sums (R10 verbatim) --------------------------------
__global__ __launch_bounds__(256) void rows_kernel(
    const int* __restrict__ ids, const float* __restrict__ gram,
    const float* __restrict__ invs,
    float* __restrict__ rowloss, int* __restrict__ rowvalid)
{
    const int i    = blockIdx.x;
    const int tid  = threadIdx.x;
    const int lane = tid & 63;
    const int wid  = tid >> 6;

    __shared__ unsigned char pat[B];
    __shared__ float sinv[B];
    __shared__ float vals[B];
    __shared__ unsigned long long cmask[8];
    __shared__ int   coff[9];
    __shared__ float part_s[4];

    #pragma unroll
    for (int q = 0; q < 2; ++q) {
        int j = tid + q * 256;
        int4 v = ((const int4*)ids)[j];
        pat[j] = (unsigned char)((v.x & 1) | ((v.y & 1) << 1)
                               | ((v.z & 1) << 2) | ((v.w & 1) << 3));
        sinv[j] = invs[j];                        // coalesced
    }
    __syncthreads();

    const int   pi   = pat[i];
    const float invi = sinv[i];

    // ballot-compact sim cos values (proven pattern)
    #pragma unroll
    for (int cc = 0; cc < 2; ++cc) {
        int chunk = wid * 2 + cc;
        int j = chunk * 64 + lane;
        unsigned long long m = __ballot(pat[j] == pi && j != i);
        if (lane == 0) cmask[chunk] = m;
    }
    __syncthreads();
    if (tid == 0) {
        int a = 0;
        #pragma unroll
        for (int c = 0; c < 8; ++c) { coff[c] = a; a += (int)__popcll(cmask[c]); }
        coff[8] = a;
    }
    __syncthreads();
    #pragma unroll
    for (int cc = 0; cc < 2; ++cc) {
        int chunk = wid * 2 + cc;
        int j = chunk * 64 + lane;
        unsigned long long m = cmask[chunk];
        if ((m >> lane) & 1ull) {
            int pos = coff[chunk] + (int)__popcll(m & ((1ull << lane) - 1ull));
            vals[pos] = gram[(size_t)i * B + j] * invi * sinv[j];
        }
    }
    __syncthreads();

    const int ns = coff[8];
    const int p0 = pat[tid], p1 = pat[tid + 256];
    const bool m0 = (p0 != pi), m1 = (p1 != pi);  // j==i auto-excluded (p==pi)
    const float c0 = gram[(size_t)i * B + tid]       * invi * sinv[tid];
    const float c1 = gram[(size_t)i * B + tid + 256] * invi * sinv[tid + 256];
    const float b0 = 0.15f * (float)__popc(p0 ^ pi) + c0;
    const float b1 = 0.15f * (float)__popc(p1 ^ pi) + c1;

    float s = 0.f;
    for (int t = 0; t < ns; ++t) {                // ~31 iters, broadcast LDS read
        float a = vals[t];
        if (m0) s += fmaxf(0.f, b0 - a);
        if (m1) s += fmaxf(0.f, b1 - a);
    }
    #pragma unroll
    for (int o = 32; o > 0; o >>= 1) s += __shfl_down(s, o);
    if (lane == 0) part_s[wid] = s;
    __syncthreads();
    if (tid == 0) {
        float tot = part_s[0] + part_s[1] + part_s[2] + part_s[3];
        const int nd = (B - 1) - ns;              // j != i is sim xor dif
        long cnt = (long)ns * (long)nd;
        rowloss[i]  = (cnt > 0) ? tot / (float)cnt : 0.f;
        rowvalid[i] = (cnt > 0) ? 1 : 0;
    }
}

// ---- K3: final mean over valid rows (R10 verbatim) ------------------------
__global__ __launch_bounds__(256) void finalize_kernel(
    const float* __restrict__ rowloss, const int* __restrict__ rowvalid,
    float* __restrict__ out)
{
    const int tid  = threadIdx.x;
    const int lane = tid & 63;
    const int wid  = tid >> 6;
    __shared__ float sb[4], vb[4];

    float s = rowloss[tid] + rowloss[tid + 256];
    float v = (float)(rowvalid[tid] + rowvalid[tid + 256]);
    #pragma unroll
    for (int o = 32; o > 0; o >>= 1) {
        s += __shfl_down(s, o);
        v += __shfl_down(v, o);
    }
    if (lane == 0) { sb[wid] = s; vb[wid] = v; }
    __syncthreads();
    if (tid == 0) {
        float ts = sb[0] + sb[1] + sb[2] + sb[3];
        float tv = vb[0] + vb[1] + vb[2] + vb[3];
        out[0] = ts / fmaxf(tv, 1.f);
    }
}

extern "C" void kernel_launch(void* const* d_in, const int* in_sizes, int n_in,
                              void* d_out, int out_size, void* d_ws, size_t ws_size,
                              hipStream_t stream) {
    const int*   ids   = (const int*)d_in[0];
    const float* feats = (const float*)d_in[1];
    float* out = (float*)d_out;

    char* ws = (char*)d_ws;
    float* gram     = (float*)ws;                           // 1 MB
    float* invs     = (float*)(ws + (1u << 20));            // 2 KB
    float* rowloss  = (float*)(ws + (1u << 20) + 2048);     // 2 KB
    int*   rowvalid = (int*)(ws + (1u << 20) + 4096);       // 2 KB

    hipLaunchKernelGGL(gram_mfma32, dim3(16 * 16), dim3(64), 0, stream,
                       feats, gram, invs);
    hipLaunchKernelGGL(rows_kernel, dim3(B), dim3(256), 0, stream,
                       ids, gram, invs, rowloss, rowvalid);
    hipLaunchKernelGGL(finalize_kernel, dim3(1), dim3(256), 0, stream,
                       rowloss, rowvalid, out);
}